// Round 1
// 624.429 us; speedup vs baseline: 1.0225x; 1.0225x over previous
//
#include <hip/hip_runtime.h>
#include <hip/hip_bf16.h>
#include <cstdint>
#include <cstddef>

// minLSTM: out = exp(heinsen_scan(log_f, log_i + log_g(h))), [h,f,i] = x @ W
// B=4 S=8192 D=1024. GEMM bf16 MFMA (fp32 accum) -> bf16 hW; fp32 log-space
// chunked scan with recurrence log_h = logaddexp(log_h + lf, lv).
// R5: GEMM ported to 256x256 8-phase schedule (T1 XCD swizzle + T2 LDS XOR
// swizzle + T3/T4 counted vmcnt + T5 setprio). 8 waves, BK=64, dbuf LDS,
// raw s_barrier (no vmcnt(0) drain in main loop).

#define BB 4
#define SS 8192
#define DD 1024
#define MM 32768   // B*S
#define KK 1024    // D
#define NN 3072    // 3*D
#define CHUNKS 256
#define CLEN 32    // SS / CHUNKS
#define NCH 4096   // B*D channels
#define NT 16      // KK / 64 K-tiles

typedef __bf16 bf16;
typedef __bf16 bf16x2 __attribute__((ext_vector_type(2)));
typedef __bf16 bf16x4 __attribute__((ext_vector_type(4)));
typedef __bf16 bf16x8 __attribute__((ext_vector_type(8)));
typedef float f32x4 __attribute__((ext_vector_type(4)));

// ---- async global->LDS, 16B per lane (wave-uniform LDS base + lane*16) ----
__device__ __forceinline__ void gload16(const bf16* g, bf16* l) {
  __builtin_amdgcn_global_load_lds(
      (const __attribute__((address_space(1))) unsigned int*)(const void*)g,
      (__attribute__((address_space(3))) unsigned int*)(void*)l,
      16, 0, 0);
}

// ---- scalar math helpers ----
__device__ __forceinline__ float sp(float x) {  // softplus, stable
  return fmaxf(x, 0.f) + __logf(1.f + __expf(-fabsf(x)));
}
__device__ __forceinline__ void gates(float h, float f, float i,
                                      float& lf, float& lv) {
  float d = sp(-f) - sp(-i);
  float spd = sp(d);
  lf = -spd;            // -softplus(diff)
  float li = d - spd;   // -softplus(-diff)
  float lg = (h >= 0.f) ? __logf(h + 0.5f) : -sp(-h);
  lv = li + lg;
}
__device__ __forceinline__ float laddexp(float a, float b) {
  float m = fmaxf(a, b);
  return m + __logf(1.f + __expf(fminf(a, b) - m));
}
// combine running state (A,V) with chunk aggregate (Ac,Vc), chunk on the right
__device__ __forceinline__ void comb(float& A, float& V, float Ac, float Vc) {
  V = laddexp(V + Ac, Vc);
  A += Ac;
}

// ---- convert x fp32 -> bf16 (vectorized) ----
__global__ __launch_bounds__(256) void k_cvt_x(const float4* __restrict__ x,
                                               bf16x4* __restrict__ xb) {
  int i = blockIdx.x * 256 + threadIdx.x;
  float4 v = x[i];
  bf16x4 o;
  o[0] = (bf16)v.x; o[1] = (bf16)v.y; o[2] = (bf16)v.z; o[3] = (bf16)v.w;
  xb[i] = o;
}

// ---- convert + transpose W [K,N] fp32 -> Wt [N,K] bf16 (LDS 32x32 tile) ----
__global__ __launch_bounds__(256) void k_cvt_wt(const float* __restrict__ W,
                                                bf16* __restrict__ Wt) {
  __shared__ float tile[32][33];
  int n0 = blockIdx.x * 32, k0 = blockIdx.y * 32;
  int tx = threadIdx.x, ty = threadIdx.y;  // (32, 8)
#pragma unroll
  for (int i = 0; i < 32; i += 8)
    tile[ty + i][tx] = W[(size_t)(k0 + ty + i) * NN + n0 + tx];
  __syncthreads();
#pragma unroll
  for (int i = 0; i < 32; i += 8)
    Wt[(size_t)(n0 + ty + i) * KK + k0 + tx] = (bf16)tile[tx][ty + i];
}

// ---- bf16 GEMM, C[m][n] = sum_k A[m][k]*Bt[n][k] --------------------------
// 256x256 tile, BK=64, 8 waves (2Mx4N), 8-phase (4 quadrant-phases per K-tile
// x unrolled dbuf), counted vmcnt, LDS XOR-swizzle slot^= (row&7).
// LDS per buffer (bf16 elems): A [256][64] @0, B [256][64] @16384. 2 buffers.
__global__ __launch_bounds__(512, 2) void k_gemm(const bf16* __restrict__ A,
                                                 const bf16* __restrict__ Bt,
                                                 bf16* __restrict__ C) {
  __shared__ __align__(16) bf16 sm[65536];  // 128 KiB
  const int tid = threadIdx.x;
  const int lane = tid & 63;
  const int w = tid >> 6;          // 0..7
  const int wm = w >> 2;           // 0..1 (M)
  const int wn = w & 3;            // 0..3 (N)
  const int c16 = lane & 15;
  const int l4 = lane >> 4;

  // XCD-aware bijective swizzle: 1536 blocks = 8 XCD * 192; nT fast inside
  // a chunk so consecutive same-XCD blocks reuse the A panel in L2.
  int bid = blockIdx.x;
  int swz = (bid & 7) * 192 + (bid >> 3);
  int mT = swz / 12;
  int nT = swz - mT * 12;
  const int mBase = mT * 256, nBase = nT * 256;

  // staging: thread covers LDS linear slot (row = tid>>3 (+64*L +128*half),
  // slot = tid&7); global source column pre-swizzled (inverse of read XOR).
  const int sr = tid >> 3;                       // 0..63
  const int scol = ((tid & 7) ^ (sr & 7)) * 8;   // swizzled k-col (elems)
  const bf16* gA = A + (size_t)(mBase + sr) * KK + scol;
  const bf16* gB = Bt + (size_t)(nBase + sr) * KK + scol;
  const int ld = tid * 8;                        // linear LDS dest (elems)

  // ds_read: addr = region + row*64 + ((slot ^ (row&7))*8); row&7 == c16&7
  const int sw8 = c16 & 7;
  const int sx0 = (l4 ^ sw8) * 8;          // ksub=0 (slots 0..3)
  const int sx1 = ((l4 + 4) ^ sw8) * 8;    // ksub=1 (slots 4..7)
  const int aRow = (wm * 64 + c16) * 64;   // + qm*8192 + mi*1024
  const int bRow = (wn * 32 + c16) * 64;   // + qn*8192 + ni*1024

  f32x4 acc[2][2][4][2];  // [qm][qn][mi][ni]
#pragma unroll
  for (int a = 0; a < 2; ++a)
#pragma unroll
    for (int b2 = 0; b2 < 2; ++b2)
#pragma unroll
      for (int m = 0; m < 4; ++m)
#pragma unroll
        for (int n = 0; n < 2; ++n)
          acc[a][b2][m][n] = (f32x4){0.f, 0.f, 0.f, 0.f};

#define STGA(h, L, bo, ko) \
  gload16(gA + (h) * 131072 + (L) * 65536 + (ko), \
          sm + (bo) + (h) * 8192 + (L) * 4096 + ld)
#define STGB(h, L, bo, ko) \
  gload16(gB + (h) * 131072 + (L) * 65536 + (ko), \
          sm + (bo) + 16384 + (h) * 8192 + (L) * 4096 + ld)
#define LDA(qm)                                                         \
  _Pragma("unroll") for (int mi = 0; mi < 4; ++mi) {                    \
    const bf16* p_ = sm + buf + (qm) * 8192 + aRow + mi * 1024;         \
    afr[mi][0] = *(const bf16x8*)(p_ + sx0);                            \
    afr[mi][1] = *(const bf16x8*)(p_ + sx1);                            \
  }
#define LDB(qn)                                                         \
  _Pragma("unroll") for (int ni = 0; ni < 2; ++ni) {                    \
    const bf16* p_ = sm + buf + 16384 + (qn) * 8192 + bRow + ni * 1024; \
    bfr[ni][0] = *(const bf16x8*)(p_ + sx0);                            \
    bfr[ni][1] = *(const bf16x8*)(p_ + sx1);                            \
  }
#define MFMAQ(qm, qn)                                                     \
  __builtin_amdgcn_s_setprio(1);                                          \
  _Pragma("unroll") for (int mi = 0; mi < 4; ++mi)                        \
  _Pragma("unroll") for (int ni = 0; ni < 2; ++ni) {                      \
    acc[qm][qn][mi][ni] = __builtin_amdgcn_mfma_f32_16x16x32_bf16(        \
        afr[mi][0], bfr[ni][0], acc[qm][qn][mi][ni], 0, 0, 0);            \
    acc[qm][qn][mi][ni] = __builtin_amdgcn_mfma_f32_16x16x32_bf16(        \
        afr[mi][1], bfr[ni][1], acc[qm][qn][mi][ni], 0, 0, 0);            \
  }                                                                       \
  __builtin_amdgcn_s_setprio(0);
#define BAR asm volatile("s_barrier" ::: "memory")
#define VMC(n) asm volatile("s_waitcnt vmcnt(" #n ")" ::: "memory")

  // prologue: stage K-tile 0 into buffer 0 (issue order A0,B0,A1,B1)
  STGA(0, 0, 0, 0); STGA(0, 1, 0, 0); STGB(0, 0, 0, 0); STGB(0, 1, 0, 0);
  STGA(1, 0, 0, 0); STGA(1, 1, 0, 0); STGB(1, 0, 0, 0); STGB(1, 1, 0, 0);
  VMC(4);  // A0,B0 resident; A1,B1 may fly
  BAR;

  bf16x8 afr[4][2], bfr[2][2];

  for (int t = 0; t < NT - 1; ++t) {
    const int buf = (t & 1) << 15;
    const int nb = buf ^ 32768;
    const int ko = (t + 1) * 64;
    // ph1: quadrant (0,0) — reads A-half0, B-half0
    LDA(0); LDB(0);
    STGA(0, 0, nb, ko); STGA(0, 1, nb, ko);
    STGB(0, 0, nb, ko); STGB(0, 1, nb, ko);
    VMC(4);  // guarantees A1(t),B1(t); leaves A0,B0(t+1) in flight
    BAR;
    MFMAQ(0, 0);
    BAR;
    // ph2: quadrant (1,0) — reads A-half1 (B regs reused)
    LDA(1);
    STGA(1, 0, nb, ko); STGA(1, 1, nb, ko);
    BAR;
    MFMAQ(1, 0);
    BAR;
    // ph3: quadrant (1,1) — reads B-half1 (A regs reused)
    LDB(1);
    STGB(1, 0, nb, ko); STGB(1, 1, nb, ko);
    BAR;
    MFMAQ(1, 1);
    BAR;
    // ph4: quadrant (0,1) — re-reads A-half0
    LDA(0);
    VMC(4);  // guarantees A0,B0(t+1); leaves A1,B1(t+1) in flight
    BAR;
    MFMAQ(0, 1);
    BAR;
  }
  {  // peeled last K-tile (t = NT-1, buf = 32768), no staging
    const int buf = 32768;
    LDA(0); LDB(0);
    VMC(0);  // drain: A1,B1 of last tile
    BAR;
    MFMAQ(0, 0);
    BAR;
    LDA(1);
    BAR;
    MFMAQ(1, 0);
    BAR;
    LDB(1);
    BAR;
    MFMAQ(1, 1);
    BAR;
    LDA(0);
    BAR;
    MFMAQ(0, 1);
  }

  // Epilogue: LDS-transpose (swizzled, stride 256) then coalesced 16B stores.
  // C/D layout: col=lane&15 (N), row=(lane>>4)*4+reg (M) [m89-verified].
  __syncthreads();
  const int rq = l4 * 4;
#pragma unroll
  for (int qm = 0; qm < 2; ++qm)
#pragma unroll
    for (int qn = 0; qn < 2; ++qn)
#pragma unroll
      for (int mi = 0; mi < 4; ++mi)
#pragma unroll
        for (int ni = 0; ni < 2; ++ni)
#pragma unroll
          for (int r = 0; r < 4; ++r) {
            int row = qm * 128 + wm * 64 + mi * 16 + rq + r;
            int col = (qn * 128 + wn * 32 + ni * 16 + c16) ^ ((row & 7) << 3);
            sm[row * 256 + col] = (bf16)acc[qm][qn][mi][ni][r];
          }
  __syncthreads();
#pragma unroll
  for (int p = 0; p < 16; ++p) {
    int row = p * 16 + (tid >> 5);
    int colL = (tid & 31) * 8;                    // logical col
    int col = colL ^ ((row & 7) << 3);            // swizzled LDS col
    bf16x8 v = *(const bf16x8*)(sm + row * 256 + col);
    *(bf16x8*)(C + (size_t)(mBase + row) * NN + nBase + colL) = v;
  }
#undef STGA
#undef STGB
#undef LDA
#undef LDB
#undef MFMAQ
#undef BAR
#undef VMC
}

// ---- scan phase 1: per (channel-pair, chunk) aggregate, pipelined ----------
// agg layout: [channel][chunk] (channel = b*DD + d)
__global__ __launch_bounds__(256, 6) void k_scan1(const bf16* __restrict__ hW,
                                                  float2* __restrict__ agg) {
  const int d0 = (blockIdx.x * 256 + threadIdx.x) * 2;
  const int b = blockIdx.y, c = blockIdx.z;
  const bf16* p = hW + (size_t)(b * SS + c * CLEN) * NN + d0;
  float A0 = 0.f, V0 = -1e30f, A1 = 0.f, V1 = -1e30f;
  bf16x2 hh = *(const bf16x2*)(p);
  bf16x2 ff = *(const bf16x2*)(p + DD);
  bf16x2 ii = *(const bf16x2*)(p + 2 * DD);
#pragma unroll 4
  for (int j = 0; j < CLEN - 1; ++j) {
    p += NN;
    bf16x2 hn = *(const bf16x2*)(p);
    bf16x2 fn = *(const bf16x2*)(p + DD);
    bf16x2 in2 = *(const bf16x2*)(p + 2 * DD);
    float lf, lv;
    gates((float)hh[0], (float)ff[0], (float)ii[0], lf, lv);
    A0 += lf; V0 = laddexp(V0 + lf, lv);
    gates((float)hh[1], (float)ff[1], (float)ii[1], lf, lv);
    A1 += lf; V1 = laddexp(V1 + lf, lv);
    hh = hn; ff = fn; ii = in2;
  }
  float lf, lv;
  gates((float)hh[0], (float)ff[0], (float)ii[0], lf, lv);
  A0 += lf; V0 = laddexp(V0 + lf, lv);
  gates((float)hh[1], (float)ff[1], (float)ii[1], lf, lv);
  A1 += lf; V1 = laddexp(V1 + lf, lv);
  const size_t ch = (size_t)b * DD + d0;
  agg[ch * CHUNKS + c] = make_float2(A0, V0);
  agg[(ch + 1) * CHUNKS + c] = make_float2(A1, V1);
}

// ---- scan phase 2: wave-parallel exclusive scan over chunks ----------------
// One wave per channel; lane holds 4 chunk aggregates; shfl tree scan.
__global__ __launch_bounds__(256) void k_scan2(const float2* __restrict__ agg,
                                               float2* __restrict__ pre) {
  const int ch = blockIdx.x * 4 + (threadIdx.x >> 6);
  const int lane = threadIdx.x & 63;
  const float4* src = (const float4*)(agg + (size_t)ch * CHUNKS);
  float4 v0 = src[lane * 2];      // chunks 4*lane, 4*lane+1
  float4 v1 = src[lane * 2 + 1];  // chunks 4*lane+2, 4*lane+3
  // lane-local fold
  float A = v0.x, V = v0.y;
  comb(A, V, v0.z, v0.w);
  comb(A, V, v1.x, v1.y);
  comb(A, V, v1.z, v1.w);
  // inclusive wave scan of lane aggregates
#pragma unroll
  for (int off = 1; off < 64; off <<= 1) {
    float Ao = __shfl_up(A, off);
    float Vo = __shfl_up(V, off);
    if (lane >= off) {
      V = laddexp(Vo + A, V);
      A = Ao + A;
    }
  }
  // exclusive lane prefix
  float exA = __shfl_up(A, 1);
  float exV = __shfl_up(V, 1);
  if (lane == 0) { exA = 0.f; exV = -1e30f; }
  // produce exclusive per-chunk prefixes
  float4 o0, o1;
  o0.x = exA; o0.y = exV;
  comb(exA, exV, v0.x, v0.y);
  o0.z = exA; o0.w = exV;
  comb(exA, exV, v0.z, v0.w);
  o1.x = exA; o1.y = exV;
  comb(exA, exV, v1.x, v1.y);
  o1.z = exA; o1.w = exV;
  float4* dst = (float4*)(pre + (size_t)ch * CHUNKS);
  dst[lane * 2] = o0;
  dst[lane * 2 + 1] = o1;
}

// ---- scan phase 3: re-run chunk with prefix init, write exp(log_h) ---------
__global__ __launch_bounds__(256, 6) void k_scan3(const bf16* __restrict__ hW,
                                                  const float2* __restrict__ pre,
                                                  float* __restrict__ out) {
  const int d0 = (blockIdx.x * 256 + threadIdx.x) * 2;
  const int b = blockIdx.y, c = blockIdx.z;
  const bf16* p = hW + (size_t)(b * SS + c * CLEN) * NN + d0;
  float* o = out + (size_t)(b * SS + c * CLEN) * DD + d0;
  const size_t ch = (size_t)b * DD + d0;
  float V0 = pre[ch * CHUNKS + c].y;
  float V1 = pre[(ch + 1) * CHUNKS + c].y;
  bf16x2 hh = *(const bf16x2*)(p);
  bf16x2 ff = *(const bf16x2*)(p + DD);
  bf16x2 ii = *(const bf16x2*)(p + 2 * DD);
#pragma unroll 4
  for (int j = 0; j < CLEN - 1; ++j) {
    p += NN;
    bf16x2 hn = *(const bf16x2*)(p);
    bf16x2 fn = *(const bf16x2*)(p + DD);
    bf16x2 in2 = *(const bf16x2*)(p + 2 * DD);
    float lf, lv;
    gates((float)hh[0], (float)ff[0], (float)ii[0], lf, lv);
    V0 = laddexp(V0 + lf, lv);
    gates((float)hh[1], (float)ff[1], (float)ii[1], lf, lv);
    V1 = laddexp(V1 + lf, lv);
    *(float2*)o = make_float2(__expf(V0), __expf(V1));
    o += DD;
    hh = hn; ff = fn; ii = in2;
  }
  float lf, lv;
  gates((float)hh[0], (float)ff[0], (float)ii[0], lf, lv);
  V0 = laddexp(V0 + lf, lv);
  gates((float)hh[1], (float)ff[1], (float)ii[1], lf, lv);
  V1 = laddexp(V1 + lf, lv);
  *(float2*)o = make_float2(__expf(V0), __expf(V1));
}

extern "C" void kernel_launch(void* const* d_in, const int* in_sizes, int n_in,
                              void* d_out, int out_size, void* d_ws,
                              size_t ws_size, hipStream_t stream) {
  const float* x = (const float*)d_in[0];
  const float* W = (const float*)d_in[1];
  float* out = (float*)d_out;
  char* ws = (char*)d_ws;

  // workspace layout: [Wt 6MB][xb 64MB][hW 192MB]; agg/pre (8MB each) overlay
  // the xb region, which is dead after the GEMM completes.
  const size_t wtB = (size_t)NN * KK * 2;   //  6,291,456
  const size_t xbB = (size_t)MM * KK * 2;   // 67,108,864
  const size_t aggB = (size_t)CHUNKS * NCH * sizeof(float2);  // 8 MiB
  bf16* Wt = (bf16*)ws;
  bf16* xb = (bf16*)(ws + wtB);
  bf16* hW = (bf16*)(ws + wtB + xbB);
  float2* agg = (float2*)(ws + wtB);          // overlays xb (dead post-GEMM)
  float2* pre = (float2*)(ws + wtB + aggB);

  k_cvt_wt<<<dim3(NN / 32, KK / 32), dim3(32, 8), 0, stream>>>(W, Wt);
  k_cvt_x<<<dim3(MM * KK / 4 / 256), dim3(256), 0, stream>>>((const float4*)x,
                                                             (bf16x4*)xb);
  k_gemm<<<dim3((NN / 256) * (MM / 256)), dim3(512), 0, stream>>>(xb, Wt, hW);
  k_scan1<<<dim3(DD / 512, BB, CHUNKS), 256, 0, stream>>>(hW, agg);
  k_scan2<<<dim3(NCH / 4), 256, 0, stream>>>(agg, pre);
  k_scan3<<<dim3(DD / 512, BB, CHUNKS), 256, 0, stream>>>(hW, pre, out);
}

// Round 3
// 533.596 us; speedup vs baseline: 1.1966x; 1.1702x over previous
//
#include <hip/hip_runtime.h>
#include <hip/hip_bf16.h>
#include <cstdint>
#include <cstddef>

// minLSTM: out = exp(heinsen_scan(log_f, log_i + log_g(h))), [h,f,i] = x @ W
// B=4 S=8192 D=1024. GEMM bf16 MFMA (fp32 accum) -> bf16 hW.
// R7 == R6 resubmit (round-2 bench died with "container failed twice", no
// compile/profile output; source audited for hangs/faults — none found).
// R6: (a) scans rewritten in LINEAR domain: F=sigmoid(-d) => F+I=1 (EMA),
//     F=(1+Q)/Z, I=(1+P)/Z, Z=2+P+Q, P=e^-f, Q=e^-i. 3 exp + 2 rcp per step,
//     zero logs (scan1: 2 logs per 32-chunk; scan3: none). 4 ch/thread.
// (b) GEMM: dual B fragment sets; quadrant order (0,0)(0,1)(1,1)(1,0) ->
//     phase ds_reads 12/4/8/0 (was 12/8/4/8), ph4 lgkm-stall-free.

#define BB 4
#define SS 8192
#define DD 1024
#define MM 32768   // B*S
#define KK 1024    // D
#define NN 3072    // 3*D
#define CHUNKS 256
#define CLEN 32    // SS / CHUNKS
#define NCH 4096   // B*D channels
#define NT 16      // KK / 64 K-tiles

typedef __bf16 bf16;
typedef __bf16 bf16x2 __attribute__((ext_vector_type(2)));
typedef __bf16 bf16x4 __attribute__((ext_vector_type(4)));
typedef __bf16 bf16x8 __attribute__((ext_vector_type(8)));
typedef float f32x4 __attribute__((ext_vector_type(4)));

// ---- async global->LDS, 16B per lane (wave-uniform LDS base + lane*16) ----
__device__ __forceinline__ void gload16(const bf16* g, bf16* l) {
  __builtin_amdgcn_global_load_lds(
      (const __attribute__((address_space(1))) unsigned int*)(const void*)g,
      (__attribute__((address_space(3))) unsigned int*)(void*)l,
      16, 0, 0);
}

// ---- linear-domain gate evaluation ----------------------------------------
// F = sigmoid(-(sp(-f)-sp(-i))) = (1+e^-i)/(2+e^-f+e^-i); I = 1-F.
// IG = I * g(h), g(h) = h>=0 ? h+0.5 : sigmoid(h).
__device__ __forceinline__ void gate2(float h, float f, float i,
                                      float& F, float& IG) {
  float P = __expf(fminf(-f, 80.f));
  float Q = __expf(fminf(-i, 80.f));
  float rZ = __builtin_amdgcn_rcpf(2.f + P + Q);
  float eh = __expf(fminf(-h, 80.f));
  float gh = (h >= 0.f) ? (h + 0.5f) : __builtin_amdgcn_rcpf(1.f + eh);
  F = (1.f + Q) * rZ;
  IG = (1.f + P) * gh * rZ;
}

// ---- log-domain combine for the cross-chunk scan (scan2) ------------------
__device__ __forceinline__ float laddexp(float a, float b) {
  float m = fmaxf(a, b);
  return m + __logf(1.f + __expf(fminf(a, b) - m));
}
__device__ __forceinline__ void comb(float& A, float& V, float Ac, float Vc) {
  V = laddexp(V + Ac, Vc);
  A += Ac;
}

// ---- convert x fp32 -> bf16 (vectorized) ----
__global__ __launch_bounds__(256) void k_cvt_x(const float4* __restrict__ x,
                                               bf16x4* __restrict__ xb) {
  int i = blockIdx.x * 256 + threadIdx.x;
  float4 v = x[i];
  bf16x4 o;
  o[0] = (bf16)v.x; o[1] = (bf16)v.y; o[2] = (bf16)v.z; o[3] = (bf16)v.w;
  xb[i] = o;
}

// ---- convert + transpose W [K,N] fp32 -> Wt [N,K] bf16 (LDS 32x32 tile) ----
__global__ __launch_bounds__(256) void k_cvt_wt(const float* __restrict__ W,
                                                bf16* __restrict__ Wt) {
  __shared__ float tile[32][33];
  int n0 = blockIdx.x * 32, k0 = blockIdx.y * 32;
  int tx = threadIdx.x, ty = threadIdx.y;  // (32, 8)
#pragma unroll
  for (int i = 0; i < 32; i += 8)
    tile[ty + i][tx] = W[(size_t)(k0 + ty + i) * NN + n0 + tx];
  __syncthreads();
#pragma unroll
  for (int i = 0; i < 32; i += 8)
    Wt[(size_t)(n0 + ty + i) * KK + k0 + tx] = (bf16)tile[tx][ty + i];
}

// ---- bf16 GEMM, C[m][n] = sum_k A[m][k]*Bt[n][k] --------------------------
// 256x256 tile, BK=64, 8 waves (2Mx4N), 8-phase, counted vmcnt, LDS
// XOR-swizzle. Dual B-frag sets: phase reads 12/4/8/0.
__global__ __launch_bounds__(512, 2) void k_gemm(const bf16* __restrict__ A,
                                                 const bf16* __restrict__ Bt,
                                                 bf16* __restrict__ C) {
  __shared__ __align__(16) bf16 sm[65536];  // 128 KiB
  const int tid = threadIdx.x;
  const int lane = tid & 63;
  const int w = tid >> 6;          // 0..7
  const int wm = w >> 2;           // 0..1 (M)
  const int wn = w & 3;            // 0..3 (N)
  const int c16 = lane & 15;
  const int l4 = lane >> 4;

  // XCD-aware bijective swizzle: 1536 blocks = 8 XCD * 192; nT fast inside
  // a chunk so consecutive same-XCD blocks reuse the A panel in L2.
  int bid = blockIdx.x;
  int swz = (bid & 7) * 192 + (bid >> 3);
  int mT = swz / 12;
  int nT = swz - mT * 12;
  const int mBase = mT * 256, nBase = nT * 256;

  // staging: thread covers LDS linear slot (row = tid>>3 (+64*L +128*half),
  // slot = tid&7); global source column pre-swizzled (inverse of read XOR).
  const int sr = tid >> 3;                       // 0..63
  const int scol = ((tid & 7) ^ (sr & 7)) * 8;   // swizzled k-col (elems)
  const bf16* gA = A + (size_t)(mBase + sr) * KK + scol;
  const bf16* gB = Bt + (size_t)(nBase + sr) * KK + scol;
  const int ld = tid * 8;                        // linear LDS dest (elems)

  // ds_read: addr = region + row*64 + ((slot ^ (row&7))*8); row&7 == c16&7
  const int sw8 = c16 & 7;
  const int sx0 = (l4 ^ sw8) * 8;          // ksub=0 (slots 0..3)
  const int sx1 = ((l4 + 4) ^ sw8) * 8;    // ksub=1 (slots 4..7)
  const int aRow = (wm * 64 + c16) * 64;   // + qm*8192 + mi*1024
  const int bRow = (wn * 32 + c16) * 64;   // + qn*8192 + ni*1024

  f32x4 acc[2][2][4][2];  // [qm][qn][mi][ni]
#pragma unroll
  for (int a = 0; a < 2; ++a)
#pragma unroll
    for (int b2 = 0; b2 < 2; ++b2)
#pragma unroll
      for (int m = 0; m < 4; ++m)
#pragma unroll
        for (int n = 0; n < 2; ++n)
          acc[a][b2][m][n] = (f32x4){0.f, 0.f, 0.f, 0.f};

#define STGA(h, L, bo, ko) \
  gload16(gA + (h) * 131072 + (L) * 65536 + (ko), \
          sm + (bo) + (h) * 8192 + (L) * 4096 + ld)
#define STGB(h, L, bo, ko) \
  gload16(gB + (h) * 131072 + (L) * 65536 + (ko), \
          sm + (bo) + 16384 + (h) * 8192 + (L) * 4096 + ld)
#define LDA(qm, AF)                                                     \
  _Pragma("unroll") for (int mi = 0; mi < 4; ++mi) {                    \
    const bf16* p_ = sm + buf + (qm) * 8192 + aRow + mi * 1024;         \
    AF[mi][0] = *(const bf16x8*)(p_ + sx0);                             \
    AF[mi][1] = *(const bf16x8*)(p_ + sx1);                             \
  }
#define LDB(qn, BF)                                                     \
  _Pragma("unroll") for (int ni = 0; ni < 2; ++ni) {                    \
    const bf16* p_ = sm + buf + 16384 + (qn) * 8192 + bRow + ni * 1024; \
    BF[ni][0] = *(const bf16x8*)(p_ + sx0);                             \
    BF[ni][1] = *(const bf16x8*)(p_ + sx1);                             \
  }
#define MFMAQ(qm, qn, AF, BF)                                             \
  __builtin_amdgcn_s_setprio(1);                                          \
  _Pragma("unroll") for (int mi = 0; mi < 4; ++mi)                        \
  _Pragma("unroll") for (int ni = 0; ni < 2; ++ni) {                      \
    acc[qm][qn][mi][ni] = __builtin_amdgcn_mfma_f32_16x16x32_bf16(        \
        AF[mi][0], BF[ni][0], acc[qm][qn][mi][ni], 0, 0, 0);              \
    acc[qm][qn][mi][ni] = __builtin_amdgcn_mfma_f32_16x16x32_bf16(        \
        AF[mi][1], BF[ni][1], acc[qm][qn][mi][ni], 0, 0, 0);              \
  }                                                                       \
  __builtin_amdgcn_s_setprio(0);
#define BAR asm volatile("s_barrier" ::: "memory")
#define VMC(n) asm volatile("s_waitcnt vmcnt(" #n ")" ::: "memory")

  // prologue: stage K-tile 0 into buffer 0 (issue order A0,B0,A1,B1)
  STGA(0, 0, 0, 0); STGA(0, 1, 0, 0); STGB(0, 0, 0, 0); STGB(0, 1, 0, 0);
  STGA(1, 0, 0, 0); STGA(1, 1, 0, 0); STGB(1, 0, 0, 0); STGB(1, 1, 0, 0);
  VMC(4);  // A0,B0 resident; A1,B1 may fly
  BAR;

  bf16x8 afr[4][2], bfr0[2][2], bfr1[2][2];

  for (int t = 0; t < NT - 1; ++t) {
    const int buf = (t & 1) << 15;
    const int nb = buf ^ 32768;
    const int ko = (t + 1) * 64;
    // ph1: Q(0,0) — reads A0 (afr), B0 (bfr0); stage A0,B0(t+1)
    LDA(0, afr); LDB(0, bfr0);
    STGA(0, 0, nb, ko); STGA(0, 1, nb, ko);
    STGB(0, 0, nb, ko); STGB(0, 1, nb, ko);
    VMC(4);  // guarantees A1(t),B1(t); leaves A0,B0(t+1) in flight
    BAR;
    MFMAQ(0, 0, afr, bfr0);
    BAR;
    // ph2: Q(0,1) — reads B1 (bfr1); afr kept; stage A1(t+1)
    LDB(1, bfr1);
    STGA(1, 0, nb, ko); STGA(1, 1, nb, ko);
    BAR;
    MFMAQ(0, 1, afr, bfr1);
    BAR;
    // ph3: Q(1,1) — reads A1 (afr overwrite); bfr1 kept; stage B1(t+1)
    LDA(1, afr);
    STGB(1, 0, nb, ko); STGB(1, 1, nb, ko);
    BAR;
    MFMAQ(1, 1, afr, bfr1);
    BAR;
    // ph4: Q(1,0) — NO ds reads (afr=A1, bfr0=B0 both live)
    VMC(4);  // guarantees A0,B0(t+1); leaves A1,B1(t+1) in flight
    BAR;
    MFMAQ(1, 0, afr, bfr0);
    BAR;
  }
  {  // peeled last K-tile (t = NT-1, buf = 32768), no staging
    const int buf = 32768;
    LDA(0, afr); LDB(0, bfr0);
    VMC(0);  // drain: A1,B1 of last tile
    BAR;
    MFMAQ(0, 0, afr, bfr0);
    BAR;
    LDB(1, bfr1);
    BAR;
    MFMAQ(0, 1, afr, bfr1);
    BAR;
    LDA(1, afr);
    BAR;
    MFMAQ(1, 1, afr, bfr1);
    BAR;
    MFMAQ(1, 0, afr, bfr0);
  }

  // Epilogue: LDS-transpose (swizzled, stride 256) then coalesced 16B stores.
  // C/D layout: col=lane&15 (N), row=(lane>>4)*4+reg (M) [m89-verified].
  __syncthreads();
  const int rq = l4 * 4;
#pragma unroll
  for (int qm = 0; qm < 2; ++qm)
#pragma unroll
    for (int qn = 0; qn < 2; ++qn)
#pragma unroll
      for (int mi = 0; mi < 4; ++mi)
#pragma unroll
        for (int ni = 0; ni < 2; ++ni)
#pragma unroll
          for (int r = 0; r < 4; ++r) {
            int row = qm * 128 + wm * 64 + mi * 16 + rq + r;
            int col = (qn * 128 + wn * 32 + ni * 16 + c16) ^ ((row & 7) << 3);
            sm[row * 256 + col] = (bf16)acc[qm][qn][mi][ni][r];
          }
  __syncthreads();
#pragma unroll
  for (int p = 0; p < 16; ++p) {
    int row = p * 16 + (tid >> 5);
    int colL = (tid & 31) * 8;                    // logical col
    int col = colL ^ ((row & 7) << 3);            // swizzled LDS col
    bf16x8 v = *(const bf16x8*)(sm + row * 256 + col);
    *(bf16x8*)(C + (size_t)(mBase + row) * NN + nBase + colL) = v;
  }
#undef STGA
#undef STGB
#undef LDA
#undef LDB
#undef MFMAQ
#undef BAR
#undef VMC
}

// ---- scan phase 1: per-chunk aggregate, linear domain, 4 ch/thread --------
// agg layout: [channel][chunk] (channel = b*DD + d), values in LOG domain.
__global__ __launch_bounds__(256, 6) void k_scan1(const bf16* __restrict__ hW,
                                                  float2* __restrict__ agg) {
  const int d0 = threadIdx.x * 4;
  const int b = blockIdx.y, c = blockIdx.z;
  const bf16* p = hW + (size_t)(b * SS + c * CLEN) * NN + d0;
  float Fp[4] = {1.f, 1.f, 1.f, 1.f};
  float v[4] = {0.f, 0.f, 0.f, 0.f};
  bf16x4 hh = *(const bf16x4*)(p);
  bf16x4 ff = *(const bf16x4*)(p + DD);
  bf16x4 ii = *(const bf16x4*)(p + 2 * DD);
#pragma unroll 4
  for (int j = 0; j < CLEN - 1; ++j) {
    p += NN;
    bf16x4 hn = *(const bf16x4*)(p);
    bf16x4 fn = *(const bf16x4*)(p + DD);
    bf16x4 in2 = *(const bf16x4*)(p + 2 * DD);
#pragma unroll
    for (int e = 0; e < 4; ++e) {
      float F, IG;
      gate2((float)hh[e], (float)ff[e], (float)ii[e], F, IG);
      v[e] = fmaf(v[e], F, IG);
      Fp[e] *= F;
    }
    hh = hn; ff = fn; ii = in2;
  }
#pragma unroll
  for (int e = 0; e < 4; ++e) {
    float F, IG;
    gate2((float)hh[e], (float)ff[e], (float)ii[e], F, IG);
    v[e] = fmaf(v[e], F, IG);
    Fp[e] *= F;
  }
  const size_t ch = (size_t)b * DD + d0;
#pragma unroll
  for (int e = 0; e < 4; ++e)
    agg[(ch + e) * CHUNKS + c] =
        make_float2(__logf(fmaxf(Fp[e], 1e-37f)), __logf(fmaxf(v[e], 1e-37f)));
}

// ---- scan phase 2: wave-parallel exclusive scan over chunks (log domain) --
__global__ __launch_bounds__(256) void k_scan2(const float2* __restrict__ agg,
                                               float2* __restrict__ pre) {
  const int ch = blockIdx.x * 4 + (threadIdx.x >> 6);
  const int lane = threadIdx.x & 63;
  const float4* src = (const float4*)(agg + (size_t)ch * CHUNKS);
  float4 v0 = src[lane * 2];      // chunks 4*lane, 4*lane+1
  float4 v1 = src[lane * 2 + 1];  // chunks 4*lane+2, 4*lane+3
  // lane-local fold
  float A = v0.x, V = v0.y;
  comb(A, V, v0.z, v0.w);
  comb(A, V, v1.x, v1.y);
  comb(A, V, v1.z, v1.w);
  // inclusive wave scan of lane aggregates
#pragma unroll
  for (int off = 1; off < 64; off <<= 1) {
    float Ao = __shfl_up(A, off);
    float Vo = __shfl_up(V, off);
    if (lane >= off) {
      V = laddexp(Vo + A, V);
      A = Ao + A;
    }
  }
  // exclusive lane prefix
  float exA = __shfl_up(A, 1);
  float exV = __shfl_up(V, 1);
  if (lane == 0) { exA = 0.f; exV = -1e30f; }
  // produce exclusive per-chunk prefixes
  float4 o0, o1;
  o0.x = exA; o0.y = exV;
  comb(exA, exV, v0.x, v0.y);
  o0.z = exA; o0.w = exV;
  comb(exA, exV, v0.z, v0.w);
  o1.x = exA; o1.y = exV;
  comb(exA, exV, v1.x, v1.y);
  o1.z = exA; o1.w = exV;
  float4* dst = (float4*)(pre + (size_t)ch * CHUNKS);
  dst[lane * 2] = o0;
  dst[lane * 2 + 1] = o1;
}

// ---- scan phase 3: re-run chunk in linear domain; out IS the state --------
__global__ __launch_bounds__(256, 6) void k_scan3(const bf16* __restrict__ hW,
                                                  const float2* __restrict__ pre,
                                                  float* __restrict__ out) {
  const int d0 = threadIdx.x * 4;
  const int b = blockIdx.y, c = blockIdx.z;
  const bf16* p = hW + (size_t)(b * SS + c * CLEN) * NN + d0;
  float* o = out + (size_t)(b * SS + c * CLEN) * DD + d0;
  const size_t ch = (size_t)b * DD + d0;
  float v[4];
#pragma unroll
  for (int e = 0; e < 4; ++e)
    v[e] = __expf(pre[(ch + e) * CHUNKS + c].y);  // exp(-1e30) = 0 for c=0
  bf16x4 hh = *(const bf16x4*)(p);
  bf16x4 ff = *(const bf16x4*)(p + DD);
  bf16x4 ii = *(const bf16x4*)(p + 2 * DD);
#pragma unroll 4
  for (int j = 0; j < CLEN - 1; ++j) {
    p += NN;
    bf16x4 hn = *(const bf16x4*)(p);
    bf16x4 fn = *(const bf16x4*)(p + DD);
    bf16x4 in2 = *(const bf16x4*)(p + 2 * DD);
    float4 ov;
#pragma unroll
    for (int e = 0; e < 4; ++e) {
      float F, IG;
      gate2((float)hh[e], (float)ff[e], (float)ii[e], F, IG);
      v[e] = fmaf(v[e], F, IG);
    }
    ov.x = v[0]; ov.y = v[1]; ov.z = v[2]; ov.w = v[3];
    *(float4*)o = ov;
    o += DD;
    hh = hn; ff = fn; ii = in2;
  }
  float4 ov;
#pragma unroll
  for (int e = 0; e < 4; ++e) {
    float F, IG;
    gate2((float)hh[e], (float)ff[e], (float)ii[e], F, IG);
    v[e] = fmaf(v[e], F, IG);
  }
  ov.x = v[0]; ov.y = v[1]; ov.z = v[2]; ov.w = v[3];
  *(float4*)o = ov;
}

extern "C" void kernel_launch(void* const* d_in, const int* in_sizes, int n_in,
                              void* d_out, int out_size, void* d_ws,
                              size_t ws_size, hipStream_t stream) {
  const float* x = (const float*)d_in[0];
  const float* W = (const float*)d_in[1];
  float* out = (float*)d_out;
  char* ws = (char*)d_ws;

  // workspace layout: [Wt 6MB][xb 64MB][hW 192MB]; agg/pre (8MB each) overlay
  // the xb region, which is dead after the GEMM completes.
  const size_t wtB = (size_t)NN * KK * 2;   //  6,291,456
  const size_t xbB = (size_t)MM * KK * 2;   // 67,108,864
  const size_t aggB = (size_t)CHUNKS * NCH * sizeof(float2);  // 8 MiB
  bf16* Wt = (bf16*)ws;
  bf16* xb = (bf16*)(ws + wtB);
  bf16* hW = (bf16*)(ws + wtB + xbB);
  float2* agg = (float2*)(ws + wtB);          // overlays xb (dead post-GEMM)
  float2* pre = (float2*)(ws + wtB + aggB);

  k_cvt_wt<<<dim3(NN / 32, KK / 32), dim3(32, 8), 0, stream>>>(W, Wt);
  k_cvt_x<<<dim3(MM * KK / 4 / 256), dim3(256), 0, stream>>>((const float4*)x,
                                                             (bf16x4*)xb);
  k_gemm<<<dim3((NN / 256) * (MM / 256)), 512, 0, stream>>>(xb, Wt, hW);
  k_scan1<<<dim3(1, BB, CHUNKS), 256, 0, stream>>>(hW, agg);
  k_scan2<<<dim3(NCH / 4), 256, 0, stream>>>(agg, pre);
  k_scan3<<<dim3(1, BB, CHUNKS), 256, 0, stream>>>(hW, pre, out);
}